// Round 6
// baseline (24170.139 us; speedup 1.0000x reference)
//
#include <hip/hip_runtime.h>
#include <hip/hip_bf16.h>
#include <math.h>

#define BB 256
#define LL 256
#define DD 4
#define HH 1024
#define SS 100
#define OUTD 3
#define X0 768          /* L*OUT */
#define K1 1792         /* 768 + 1024 */
#define K2 2048
#define NG 4096

typedef __attribute__((ext_vector_type(4))) float f32x4;
typedef __attribute__((ext_vector_type(8))) short bf16x8;
typedef __hip_bfloat16 bf16;

__device__ __forceinline__ float sigmoidf_(float x){ return 1.0f/(1.0f + __expf(-x)); }

__device__ __forceinline__ void gll16(const void* g, void* l){
  __builtin_amdgcn_global_load_lds((const __attribute__((address_space(1))) unsigned int*)g,
                                   (__attribute__((address_space(3))) unsigned int*)l, 16, 0, 0);
}

// ---- manual grid barrier (sense-reversing, device scope) ----
// cnt at bar[0], gen at bar[32] (128B apart to decontend spin line).
__device__ __forceinline__ void grid_barrier(unsigned* bar, int tid, int nblk){
  __syncthreads();                       // drains vmcnt/lgkm: block's stores are in L2
  if (tid == 0){
    unsigned* cnt = bar;
    unsigned* gen = bar + 32;
    unsigned g = __hip_atomic_load(gen, __ATOMIC_RELAXED, __HIP_MEMORY_SCOPE_AGENT);
    __threadfence();                     // agent release: L2 writeback
    unsigned a = __hip_atomic_fetch_add(cnt, 1u, __ATOMIC_ACQ_REL, __HIP_MEMORY_SCOPE_AGENT);
    if (a == (unsigned)(nblk - 1)){
      __hip_atomic_store(cnt, 0u, __ATOMIC_RELAXED, __HIP_MEMORY_SCOPE_AGENT);
      __hip_atomic_store(gen, g + 1u, __ATOMIC_RELEASE, __HIP_MEMORY_SCOPE_AGENT);
    } else {
      while (__hip_atomic_load(gen, __ATOMIC_ACQUIRE, __HIP_MEMORY_SCOPE_AGENT) == g)
        __builtin_amdgcn_s_sleep(1);
    }
    __threadfence();                     // agent acquire: invalidate L1/L2
  }
  __syncthreads();
}

// =====================================================================
// 64x64-tile GEMM core (round-4 verified pipeline).
// Block: 4 waves = (2 m-halves wm) x (2 K-halves wk, split-K).
// W staged to LDS: per wk-half double-buffered 64rows x 256B stages,
// wave wm stages chunks wm*8+j; XOR swizzle slot^(row&7).
// A direct global->reg. acc[2][4] covers 32 rows x 64 cols per wave.
// LDS layout: [wk][buf][16KB] = 64KB total; gbuf (16KB) aliases smem+0
// after the K-loop (safe: vmcnt(0) drained + __syncthreads before reuse).
// =====================================================================
template<int K, int KH>
__device__ __forceinline__ void gemm_tile64(
    const bf16* __restrict__ Acat, const bf16* __restrict__ Wr,
    char* __restrict__ smem, int m0, int n0, int wm, int wk, int lane,
    f32x4 acc[2][4])
{
  constexpr int NT = KH / 128;
  const int lr = lane & 15, kq16 = lane >> 4;

  const char* srcW[8];
  int ldsoff[8];
  #pragma unroll
  for (int j = 0; j < 8; j++){
    int c = wm*8 + j;
    int row = c*4 + (lane >> 4);
    int slot = (lane & 15) ^ (row & 7);
    srcW[j] = (const char*)(Wr + (size_t)(n0 + row) * K + wk * KH) + slot * 16;
    ldsoff[j] = c * 1024;
  }
  const char* aptr[2];
  #pragma unroll
  for (int mt = 0; mt < 2; mt++)
    aptr[mt] = (const char*)(Acat + (size_t)(m0 + wm*32 + mt*16 + lr) * K + wk * KH) + kq16 * 16;

  int woff[4][4];
  #pragma unroll
  for (int nt = 0; nt < 4; nt++)
    #pragma unroll
    for (int s = 0; s < 4; s++){
      int row = nt*16 + lr;
      woff[nt][s] = row*256 + (((s*4 + kq16) ^ (row & 7)) << 4);
    }

  bf16x8 Aa[2][4], Ab[2][4];
  {
    char* db = smem + wk*32768;
    #pragma unroll
    for (int j = 0; j < 8; j++) gll16(srcW[j], db + ldsoff[j]);
    __builtin_amdgcn_sched_barrier(0);
    #pragma unroll
    for (int mt = 0; mt < 2; mt++)
      #pragma unroll
      for (int s = 0; s < 4; s++)
        Aa[mt][s] = *(const bf16x8*)(aptr[mt] + s*64);
  }

#define CELL_BODY(I, CUR, NXT, LAST)                                          \
  {                                                                           \
    __builtin_amdgcn_s_barrier();                                             \
    if (!(LAST)) {                                                            \
      char* db = smem + wk*32768 + (((I)+1)&1)*16384;                         \
      _Pragma("unroll")                                                       \
      for (int j = 0; j < 8; j++)                                             \
        gll16(srcW[j] + (size_t)((I)+1)*256, db + ldsoff[j]);                 \
      __builtin_amdgcn_sched_barrier(0);                                      \
      _Pragma("unroll")                                                       \
      for (int mt = 0; mt < 2; mt++)                                          \
        _Pragma("unroll")                                                     \
        for (int s = 0; s < 4; s++)                                           \
          NXT[mt][s] = *(const bf16x8*)(aptr[mt] + (size_t)((I)+1)*256 + s*64);\
      asm volatile("s_waitcnt vmcnt(16)" ::: "memory");                       \
    } else {                                                                  \
      asm volatile("s_waitcnt vmcnt(0)" ::: "memory");                        \
    }                                                                         \
    __builtin_amdgcn_s_barrier();                                             \
    __builtin_amdgcn_sched_barrier(0);                                        \
    const char* wb = smem + wk*32768 + ((I)&1)*16384;                         \
    bf16x8 Wf[4][4];                                                          \
    _Pragma("unroll")                                                         \
    for (int nt = 0; nt < 4; nt++)                                            \
      _Pragma("unroll")                                                       \
      for (int s = 0; s < 4; s++)                                             \
        Wf[nt][s] = *(const bf16x8*)(wb + woff[nt][s]);                       \
    _Pragma("unroll")                                                         \
    for (int s = 0; s < 4; s++)                                               \
      _Pragma("unroll")                                                       \
      for (int mt = 0; mt < 2; mt++)                                          \
        _Pragma("unroll")                                                     \
        for (int nt = 0; nt < 4; nt++)                                        \
          acc[mt][nt] = __builtin_amdgcn_mfma_f32_16x16x32_bf16(              \
              CUR[mt][s], Wf[nt][s], acc[mt][nt], 0,0,0);                     \
    __builtin_amdgcn_sched_barrier(0);                                        \
  }

  {
    int i = 0;
    for (; i + 2 <= NT; i += 2){
      CELL_BODY(i,   Aa, Ab, false);
      CELL_BODY(i+1, Ab, Aa, ((i+2==NT) && !(NT & 1)));
    }
    if (NT & 1) CELL_BODY(NT-1, Aa, Ab, true);
  }
#undef CELL_BODY
}

__device__ __forceinline__ void splitk_reduce(
    f32x4 acc[2][4], float* gbuf, int wm, int wk, int lane)
{
  const int rq = lane >> 4, cr = lane & 15;
  __syncthreads();   // all K-loop LDS reads + gll writes done -> safe to alias gbuf
  if (wk == 0){
    #pragma unroll
    for (int mt = 0; mt < 2; mt++)
      #pragma unroll
      for (int nt = 0; nt < 4; nt++)
        #pragma unroll
        for (int j = 0; j < 4; j++)
          gbuf[(wm*32 + mt*16 + rq*4 + j)*64 + nt*16 + cr] = acc[mt][nt][j];
  }
  __syncthreads();
  if (wk == 1){
    #pragma unroll
    for (int mt = 0; mt < 2; mt++)
      #pragma unroll
      for (int nt = 0; nt < 4; nt++)
        #pragma unroll
        for (int j = 0; j < 4; j++)
          gbuf[(wm*32 + mt*16 + rq*4 + j)*64 + nt*16 + cr] += acc[mt][nt][j];
  }
  __syncthreads();
}

// ---- LSTM cell phase: GEMM + split-K reduce + fused gate pointwise ----
template<int K, int KH, bool WTANH>
__device__ void cell_phase(
    const bf16* __restrict__ Acat, const bf16* __restrict__ Wr,
    const float* __restrict__ biasr, float* __restrict__ cst,
    bf16* __restrict__ dstA, int ldA, bf16* __restrict__ dstB, int ldB,
    char* smem, int m0, int n0, int wm, int wk, int lane, int tid)
{
  f32x4 acc[2][4] = {};
  gemm_tile64<K, KH>(Acat, Wr, smem, m0, n0, wm, wk, lane, acc);
  float* gbuf = (float*)smem;             // aliases stage buffers (dead now)
  splitk_reduce(acc, gbuf, wm, wk, lane);

  #pragma unroll
  for (int e = 0; e < 4; e++){
    int idx = e*256 + tid;                // 64 rows x 16 cols
    int r = idx >> 4, cl = idx & 15;
    f32x4 g  = *(const f32x4*)&gbuf[r*64 + cl*4];
    f32x4 bi = *(const f32x4*)&biasr[n0 + cl*4];
    int m = m0 + r;
    int col = (n0 >> 2) + cl;             // ntile*16 + cl
    float gi = g[0] + bi[0];
    float gf = g[1] + bi[1];
    float gg = g[2] + bi[2];
    float go = g[3] + bi[3];
    float cold = cst[m*HH + col];
    float cn = sigmoidf_(gf)*cold + sigmoidf_(gi)*tanhf(gg);
    float hn = sigmoidf_(go)*tanhf(cn);
    cst[m*HH + col] = cn;
    dstA[(size_t)m*ldA + col] = __float2bfloat16(hn);
    dstB[(size_t)m*ldB + col] = __float2bfloat16(WTANH ? tanhf(hn) : hn);
  }
}

// ---- dec phase: blocks 0..47, GEMM 64x64xK1024 + diffusion epilogue ----
__device__ void dec_phase(
    const bf16* __restrict__ th, const bf16* __restrict__ Wl,
    const float* __restrict__ alphas, const float* __restrict__ betas,
    const float* __restrict__ barals, const float* __restrict__ snoise,
    float* __restrict__ prev, float* __restrict__ out, bf16* __restrict__ xnext,
    char* smem, int m0, int n0, int wm, int wk, int lane, int tid, int t)
{
  f32x4 acc[2][4] = {};
  gemm_tile64<HH, 512>(th, Wl, smem, m0, n0, wm, wk, lane, acc);
  float* gbuf = (float*)smem;
  splitk_reduce(acc, gbuf, wm, wk, lane);

  const int idxs = SS - t;
  float a = alphas[idxs], ba = barals[idxs], be = betas[idxs];
  float coef = (1.0f - a) / sqrtf(1.0f - ba);
  float isq  = 1.0f / sqrtf(a);
  float nf = (t+1 < SS) ? sqrtf(be) : 0.0f;
  float* outp = out + (size_t)(SS-1-t) * (BB*X0);

  #pragma unroll
  for (int e = 0; e < 16; e++){
    int idx = e*256 + tid;                // 64 rows x 64 cols
    int r = idx >> 6, c = idx & 63;
    int m = m0 + r, n = n0 + c;
    float d = gbuf[r*64 + c];
    float pv = prev[m*X0 + n];
    float dec = (pv - coef*d)*isq + nf*snoise[t*BB + m];
    outp[m*X0 + n] = dec;
    prev[m*X0 + n] = dec;
    xnext[(size_t)m*K1 + n] = __float2bfloat16(dec);
  }
}

struct PersistArgs {
  const bf16* W0r; const bf16* W1r; const bf16* Wl;
  const float* bias0; const float* bias1;
  float* c0; float* c1;
  bf16* xcat0; bf16* xcat1; bf16* x2_0; bf16* x2_1; bf16* th;
  const float* alphas; const float* betas; const float* barals; const float* snoise;
  float* prev; float* out;
  unsigned* bar;
};

// =====================================================================
// persistent kernel: all 99 steps, grid 256 x 256 thr, manual grid barrier.
// 256 blocks = 256 CUs, 64KB LDS (2 blocks/CU capacity) -> all co-resident.
// =====================================================================
__global__ __launch_bounds__(256, 1) void persist(PersistArgs P)
{
  __shared__ __align__(16) char smem[65536];

  const int tid = threadIdx.x;
  const int wave = tid >> 6, lane = tid & 63;
  const int wm = wave & 1, wk = wave >> 1;

  const int bid = blockIdx.x;
  const int xcd = bid & 7, within = bid >> 3;
  const int ntile = xcd * 8 + (within & 7);
  const int mtile = within >> 3;            // 0..3
  const int m0 = mtile * 64;
  const int n0 = ntile * 64;

  const int dmt = bid / 12, dnt = bid % 12; // dec mapping, active if bid<48

  for (int t = 1; t < SS; t++){
    bf16* xc  = (t & 1) ? P.xcat1 : P.xcat0;
    bf16* xn  = (t & 1) ? P.xcat0 : P.xcat1;
    bf16* x2c = (t & 1) ? P.x2_1 : P.x2_0;
    bf16* x2n = (t & 1) ? P.x2_0 : P.x2_1;

    cell_phase<K1, 896, false>(xc, P.W0r, P.bias0, P.c0, x2c, K2, xn + X0, K1,
                               smem, m0, n0, wm, wk, lane, tid);
    grid_barrier(P.bar, tid, 256);
    cell_phase<K2, 1024, true>(x2c, P.W1r, P.bias1, P.c1, x2n + HH, K2, P.th, HH,
                               smem, m0, n0, wm, wk, lane, tid);
    grid_barrier(P.bar, tid, 256);
    if (bid < 48)
      dec_phase(P.th, P.Wl, P.alphas, P.betas, P.barals, P.snoise,
                P.prev, P.out, xn, smem, dmt*64, dnt*64, wm, wk, lane, tid, t);
    grid_barrier(P.bar, tid, 256);
  }
}

// =====================================================================
// setup-phase helpers (unchanged from round 4)
// =====================================================================
__device__ __forceinline__ void gemm32x32(const bf16* __restrict__ A, int lda,
                                          const bf16* __restrict__ W, int ldw,
                                          int m0, int wr0, int K,
                                          f32x4 acc[2][2], int lane)
{
  int r  = lane & 15;
  int kq = lane >> 4;
  const bf16* a0 = A + (size_t)(m0 + r)      * lda + kq*8;
  const bf16* a1 = A + (size_t)(m0 + 16 + r) * lda + kq*8;
  const bf16* b0 = W + (size_t)(wr0 + r)      * ldw + kq*8;
  const bf16* b1 = W + (size_t)(wr0 + 16 + r) * ldw + kq*8;
  for (int kk = 0; kk < K; kk += 32) {
    bf16x8 av0 = *(const bf16x8*)(a0 + kk);
    bf16x8 av1 = *(const bf16x8*)(a1 + kk);
    bf16x8 bv0 = *(const bf16x8*)(b0 + kk);
    bf16x8 bv1 = *(const bf16x8*)(b1 + kk);
    acc[0][0] = __builtin_amdgcn_mfma_f32_16x16x32_bf16(av0, bv0, acc[0][0], 0,0,0);
    acc[0][1] = __builtin_amdgcn_mfma_f32_16x16x32_bf16(av0, bv1, acc[0][1], 0,0,0);
    acc[1][0] = __builtin_amdgcn_mfma_f32_16x16x32_bf16(av1, bv0, acc[1][0], 0,0,0);
    acc[1][1] = __builtin_amdgcn_mfma_f32_16x16x32_bf16(av1, bv1, acc[1][1], 0,0,0);
  }
}

template<int EPI>
__global__ __launch_bounds__(256) void rgemm_kernel(
    const bf16* __restrict__ A, const bf16* __restrict__ W,
    const float* __restrict__ bias, const float* __restrict__ resid,
    bf16* __restrict__ d1, int ld1, bf16* __restrict__ d2, int ld2,
    float* __restrict__ f1, float* __restrict__ f2)
{
  int tid=threadIdx.x, wave=tid>>6, lane=tid&63;
  int m0 = blockIdx.x*32;
  int n0 = (blockIdx.y*4+wave)*32;
  f32x4 acc[2][2] = {};
  gemm32x32(A, HH, W, HH, m0, n0, HH, acc, lane);
  int cr=lane&15, rq=lane>>4;
  for (int r=0;r<2;r++) for (int c=0;c<2;c++) for (int j=0;j<4;j++) {
    int m = m0 + r*16+rq*4+j, n = n0 + c*16+cr;
    float v = acc[r][c][j] + bias[n];
    if (EPI==0) {
      float h = fmaxf(v,0.f) + resid[m*HH+n];
      d1[(size_t)m*ld1+n] = __float2bfloat16(h);
    } else if (EPI==1) {
      float tv = tanhf(v);
      if (n < HH) d1[(size_t)m*ld1+n] = __float2bfloat16(tv);
      else        d2[(size_t)m*ld2 + (n-HH)] = __float2bfloat16(tv);
    } else {
      float tv = tanhf(v);
      if (n < HH) f1[m*HH+n] = tv;
      else        f2[m*HH + (n-HH)] = tv;
    }
  }
}

// W rows interleaved: n' = col*4 + gate
__global__ void prep_w0_kernel(const float* __restrict__ Wih0, const float* __restrict__ Whh0,
                               bf16* __restrict__ W0r){
  int i = blockIdx.x*256 + threadIdx.x;
  if (i >= NG*K1) return;
  int np = i / K1, k = i % K1;
  int col = np >> 2, g = np & 3;
  int srow = g*HH + col;
  float v = (k < X0) ? Wih0[srow*X0 + k] : Whh0[srow*HH + (k - X0)];
  W0r[i] = __float2bfloat16(v);
}
__global__ void prep_w1_kernel(const float* __restrict__ Wih1, const float* __restrict__ Whh1,
                               bf16* __restrict__ W1r){
  int i = blockIdx.x*256 + threadIdx.x;
  if (i >= NG*K2) return;
  int np = i / K2, k = i % K2;
  int col = np >> 2, g = np & 3;
  int srow = g*HH + col;
  float v = (k < HH) ? Wih1[srow*HH + k] : Whh1[srow*HH + (k - HH)];
  W1r[i] = __float2bfloat16(v);
}
__global__ void cvt_kernel(const float* __restrict__ s, bf16* __restrict__ d, int n){
  int i = blockIdx.x*256 + threadIdx.x;
  if (i < n) d[i] = __float2bfloat16(s[i]);
}
__global__ void prep_bias_kernel(const float* bih0, const float* bhh0,
                                 const float* bih1, const float* bhh1,
                                 float* b0, float* b1, unsigned* bar){
  int i = blockIdx.x*256 + threadIdx.x;
  if (i < NG){
    int col = i >> 2, g = i & 3;
    int s = g*HH + col;
    b0[i] = bih0[s] + bhh0[s];
    b1[i] = bih1[s] + bhh1[s];
  }
  if (i < 64) bar[i] = 0u;   // zero barrier state (cnt, gen) every call
}
__global__ void init_x_kernel(const float* __restrict__ z, float* __restrict__ prev,
                              bf16* __restrict__ xcat1, float* __restrict__ out){
  int i = blockIdx.x*256 + threadIdx.x;
  if (i >= BB*X0) return;
  int m = i / X0, col = i % X0;
  int l = col / OUTD, d = col % OUTD;
  float v = z[(size_t)(m*LL + l)*DD + d];
  prev[i] = v;
  out[(size_t)(SS-1)*BB*X0 + i] = v;
  xcat1[(size_t)m*K1 + col] = __float2bfloat16(v);
}
__global__ void r1_kernel(const float* __restrict__ n0,
    const float* __restrict__ A1a, const float* __restrict__ b1a,
    const float* __restrict__ A1b, const float* __restrict__ b1b,
    float* __restrict__ h1fa, bf16* __restrict__ h1ba,
    float* __restrict__ h1fb, bf16* __restrict__ h1bb){
  int gid = blockIdx.x*256 + threadIdx.x;
  if (gid >= BB*2*HH) return;
  int m = gid >> 11;
  int col = gid & 2047;
  const float* A1; const float* b1; float* hf; bf16* hb; int c;
  if (col < HH){ A1=A1a; b1=b1a; hf=h1fa; hb=h1ba; c=col; }
  else         { A1=A1b; b1=b1b; hf=h1fb; hb=h1bb; c=col-HH; }
  float v = b1[c];
  for (int d=0; d<DD; d++) v += n0[m*DD + d] * A1[c*DD + d];
  v = fmaxf(v, 0.f);
  hf[m*HH + c] = v;
  hb[m*HH + c] = __float2bfloat16(v);
}

static inline size_t alup(size_t x){ return (x + 255) & ~(size_t)255; }

extern "C" void kernel_launch(void* const* d_in, const int* in_sizes, int n_in,
                              void* d_out, int out_size, void* d_ws, size_t ws_size,
                              hipStream_t stream) {
  const float* z      = (const float*)d_in[4];
  const float* n0     = (const float*)d_in[5];
  const float* snoise = (const float*)d_in[6];
  const float* alphas = (const float*)d_in[7];
  const float* betas  = (const float*)d_in[8];
  const float* barals = (const float*)d_in[9];
  const float* A1a = (const float*)d_in[10]; const float* b1a = (const float*)d_in[11];
  const float* A2a = (const float*)d_in[12]; const float* b2a = (const float*)d_in[13];
  const float* A3a = (const float*)d_in[14]; const float* b3a = (const float*)d_in[15];
  const float* A1b = (const float*)d_in[16]; const float* b1b = (const float*)d_in[17];
  const float* A2b = (const float*)d_in[18]; const float* b2b = (const float*)d_in[19];
  const float* A3b = (const float*)d_in[20]; const float* b3b = (const float*)d_in[21];
  const float* Wih0 = (const float*)d_in[22]; const float* Whh0 = (const float*)d_in[23];
  const float* bih0 = (const float*)d_in[24]; const float* bhh0 = (const float*)d_in[25];
  const float* Wih1 = (const float*)d_in[26]; const float* Whh1 = (const float*)d_in[27];
  const float* bih1 = (const float*)d_in[28]; const float* bhh1 = (const float*)d_in[29];
  const float* Wlin = (const float*)d_in[30];
  float* out = (float*)d_out;

  char* p = (char*)d_ws;
  size_t off = 0;
  auto take = [&](size_t bytes)->char*{ char* r = p + off; off = alup(off + bytes); return r; };
  bf16* W0cat = (bf16*)take((size_t)NG*K1*2);
  bf16* W1cat = (bf16*)take((size_t)NG*K2*2);
  bf16* WlinB = (bf16*)take((size_t)X0*HH*2);
  bf16* A2aB  = (bf16*)take((size_t)HH*HH*2);
  bf16* A2bB  = (bf16*)take((size_t)HH*HH*2);
  bf16* A3aB  = (bf16*)take((size_t)2*HH*HH*2);
  bf16* A3bB  = (bf16*)take((size_t)2*HH*HH*2);
  float* bias0 = (float*)take(NG*4);
  float* bias1 = (float*)take(NG*4);
  bf16* xcat0 = (bf16*)take((size_t)BB*K1*2);
  bf16* xcat1 = (bf16*)take((size_t)BB*K1*2);
  bf16* x2_0  = (bf16*)take((size_t)BB*K2*2);
  bf16* x2_1  = (bf16*)take((size_t)BB*K2*2);
  bf16* th    = (bf16*)take((size_t)BB*HH*2);
  float* c0   = (float*)take((size_t)BB*HH*4);
  float* c1   = (float*)take((size_t)BB*HH*4);
  float* prev = (float*)take((size_t)BB*X0*4);
  float* h1fa = (float*)take((size_t)BB*HH*4);
  float* h1fb = (float*)take((size_t)BB*HH*4);
  bf16* h1ba  = (bf16*)take((size_t)BB*HH*2);
  bf16* h1bb  = (bf16*)take((size_t)BB*HH*2);
  bf16* h2ba  = (bf16*)take((size_t)BB*HH*2);
  bf16* h2bb  = (bf16*)take((size_t)BB*HH*2);
  unsigned* bar = (unsigned*)take(256);
  (void)ws_size; (void)in_sizes; (void)n_in; (void)out_size;

  prep_w0_kernel<<<(NG*K1+255)/256, 256, 0, stream>>>(Wih0, Whh0, W0cat);
  prep_w1_kernel<<<(NG*K2+255)/256, 256, 0, stream>>>(Wih1, Whh1, W1cat);
  cvt_kernel<<<(X0*HH+255)/256, 256, 0, stream>>>(Wlin, WlinB, X0*HH);
  cvt_kernel<<<(HH*HH+255)/256, 256, 0, stream>>>(A2a, A2aB, HH*HH);
  cvt_kernel<<<(HH*HH+255)/256, 256, 0, stream>>>(A2b, A2bB, HH*HH);
  cvt_kernel<<<(2*HH*HH+255)/256, 256, 0, stream>>>(A3a, A3aB, 2*HH*HH);
  cvt_kernel<<<(2*HH*HH+255)/256, 256, 0, stream>>>(A3b, A3bB, 2*HH*HH);
  prep_bias_kernel<<<(NG+255)/256, 256, 0, stream>>>(bih0, bhh0, bih1, bhh1, bias0, bias1, bar);
  init_x_kernel<<<(BB*X0+255)/256, 256, 0, stream>>>(z, prev, xcat1, out);
  r1_kernel<<<(BB*2*HH+255)/256, 256, 0, stream>>>(n0, A1a, b1a, A1b, b1b, h1fa, h1ba, h1fb, h1bb);
  rgemm_kernel<0><<<dim3(8,8), 256, 0, stream>>>(h1ba, A2aB, b2a, h1fa, h2ba, HH, nullptr, 0, nullptr, nullptr);
  rgemm_kernel<0><<<dim3(8,8), 256, 0, stream>>>(h1bb, A2bB, b2b, h1fb, h2bb, HH, nullptr, 0, nullptr, nullptr);
  rgemm_kernel<1><<<dim3(8,16), 256, 0, stream>>>(h2ba, A3aB, b3a, nullptr, xcat1 + X0, K1, x2_1 + HH, K2, nullptr, nullptr);
  rgemm_kernel<2><<<dim3(8,16), 256, 0, stream>>>(h2bb, A3bB, b3b, nullptr, nullptr, 0, nullptr, 0, c0, c1);

  PersistArgs pa;
  pa.W0r = W0cat; pa.W1r = W1cat; pa.Wl = WlinB;
  pa.bias0 = bias0; pa.bias1 = bias1;
  pa.c0 = c0; pa.c1 = c1;
  pa.xcat0 = xcat0; pa.xcat1 = xcat1; pa.x2_0 = x2_0; pa.x2_1 = x2_1; pa.th = th;
  pa.alphas = alphas; pa.betas = betas; pa.barals = barals; pa.snoise = snoise;
  pa.prev = prev; pa.out = out;
  pa.bar = bar;
  persist<<<256, 256, 0, stream>>>(pa);
}

// Round 7
// 9618.483 us; speedup vs baseline: 2.5129x; 2.5129x over previous
//
#include <hip/hip_runtime.h>
#include <hip/hip_bf16.h>
#include <math.h>

#define BB 256
#define LL 256
#define DD 4
#define HH 1024
#define SS 100
#define OUTD 3
#define X0 768          /* L*OUT */
#define K1 1792         /* 768 + 1024 */
#define K2 2048
#define NG 4096

typedef __attribute__((ext_vector_type(4))) float f32x4;
typedef __attribute__((ext_vector_type(8))) short bf16x8;
typedef __hip_bfloat16 bf16;

__device__ __forceinline__ float sigmoidf_(float x){ return 1.0f/(1.0f + __expf(-x)); }

__device__ __forceinline__ void gll16(const void* g, void* l){
  __builtin_amdgcn_global_load_lds((const __attribute__((address_space(1))) unsigned int*)g,
                                   (__attribute__((address_space(3))) unsigned int*)l, 16, 0, 0);
}

// ---- manual grid barrier (sense-reversing, device scope) ----
// r6 bug: spin used ACQUIRE loads -> buffer_inv per poll -> L2 perpetually
// invalidated (FETCH 3.1GB @158GB/s, 80us/barrier). Fix: RELAXED spin +
// s_sleep backoff; ONE acquire threadfence after the flip is observed.
__device__ __forceinline__ void grid_barrier(unsigned* bar, int tid, int nblk){
  __syncthreads();                       // drains vmcnt: block's stores are in L2
  if (tid == 0){
    unsigned* cnt = bar;
    unsigned* gen = bar + 32;
    unsigned g = __hip_atomic_load(gen, __ATOMIC_RELAXED, __HIP_MEMORY_SCOPE_AGENT);
    __threadfence();                     // release: L2 writeback
    unsigned a = __hip_atomic_fetch_add(cnt, 1u, __ATOMIC_RELAXED, __HIP_MEMORY_SCOPE_AGENT);
    if (a == (unsigned)(nblk - 1)){
      __hip_atomic_store(cnt, 0u, __ATOMIC_RELAXED, __HIP_MEMORY_SCOPE_AGENT);
      __hip_atomic_store(gen, g + 1u, __ATOMIC_RELAXED, __HIP_MEMORY_SCOPE_AGENT);
    } else {
      while (__hip_atomic_load(gen, __ATOMIC_RELAXED, __HIP_MEMORY_SCOPE_AGENT) == g)
        __builtin_amdgcn_s_sleep(16);    // ~0.4us poll granularity, no inv traffic
    }
    __threadfence();                     // acquire: one L1/L2 inv per block per barrier
  }
  __syncthreads();
}

// =====================================================================
// 64x64-tile GEMM core (round-4 verified pipeline).
// Block: 4 waves = (2 m-halves wm) x (2 K-halves wk, split-K).
// W staged to LDS: per wk-half double-buffered 64rows x 256B stages,
// wave wm stages chunks wm*8+j; XOR swizzle slot^(row&7).
// A direct global->reg. acc[2][4] covers 32 rows x 64 cols per wave.
// LDS layout: [wk][buf][16KB] = 64KB total; gbuf (16KB) aliases smem+0
// after the K-loop (safe: vmcnt(0) drained + __syncthreads before reuse).
// =====================================================================
template<int K, int KH>
__device__ __forceinline__ void gemm_tile64(
    const bf16* __restrict__ Acat, const bf16* __restrict__ Wr,
    char* __restrict__ smem, int m0, int n0, int wm, int wk, int lane,
    f32x4 acc[2][4])
{
  constexpr int NT = KH / 128;
  const int lr = lane & 15, kq16 = lane >> 4;

  const char* srcW[8];
  int ldsoff[8];
  #pragma unroll
  for (int j = 0; j < 8; j++){
    int c = wm*8 + j;
    int row = c*4 + (lane >> 4);
    int slot = (lane & 15) ^ (row & 7);
    srcW[j] = (const char*)(Wr + (size_t)(n0 + row) * K + wk * KH) + slot * 16;
    ldsoff[j] = c * 1024;
  }
  const char* aptr[2];
  #pragma unroll
  for (int mt = 0; mt < 2; mt++)
    aptr[mt] = (const char*)(Acat + (size_t)(m0 + wm*32 + mt*16 + lr) * K + wk * KH) + kq16 * 16;

  int woff[4][4];
  #pragma unroll
  for (int nt = 0; nt < 4; nt++)
    #pragma unroll
    for (int s = 0; s < 4; s++){
      int row = nt*16 + lr;
      woff[nt][s] = row*256 + (((s*4 + kq16) ^ (row & 7)) << 4);
    }

  bf16x8 Aa[2][4], Ab[2][4];
  {
    char* db = smem + wk*32768;
    #pragma unroll
    for (int j = 0; j < 8; j++) gll16(srcW[j], db + ldsoff[j]);
    __builtin_amdgcn_sched_barrier(0);
    #pragma unroll
    for (int mt = 0; mt < 2; mt++)
      #pragma unroll
      for (int s = 0; s < 4; s++)
        Aa[mt][s] = *(const bf16x8*)(aptr[mt] + s*64);
  }

#define CELL_BODY(I, CUR, NXT, LAST)                                          \
  {                                                                           \
    __builtin_amdgcn_s_barrier();                                             \
    if (!(LAST)) {                                                            \
      char* db = smem + wk*32768 + (((I)+1)&1)*16384;                         \
      _Pragma("unroll")                                                       \
      for (int j = 0; j < 8; j++)                                             \
        gll16(srcW[j] + (size_t)((I)+1)*256, db + ldsoff[j]);                 \
      __builtin_amdgcn_sched_barrier(0);                                      \
      _Pragma("unroll")                                                       \
      for (int mt = 0; mt < 2; mt++)                                          \
        _Pragma("unroll")                                                     \
        for (int s = 0; s < 4; s++)                                           \
          NXT[mt][s] = *(const bf16x8*)(aptr[mt] + (size_t)((I)+1)*256 + s*64);\
      asm volatile("s_waitcnt vmcnt(16)" ::: "memory");                       \
    } else {                                                                  \
      asm volatile("s_waitcnt vmcnt(0)" ::: "memory");                        \
    }                                                                         \
    __builtin_amdgcn_s_barrier();                                             \
    __builtin_amdgcn_sched_barrier(0);                                        \
    const char* wb = smem + wk*32768 + ((I)&1)*16384;                         \
    bf16x8 Wf[4][4];                                                          \
    _Pragma("unroll")                                                         \
    for (int nt = 0; nt < 4; nt++)                                            \
      _Pragma("unroll")                                                       \
      for (int s = 0; s < 4; s++)                                             \
        Wf[nt][s] = *(const bf16x8*)(wb + woff[nt][s]);                       \
    _Pragma("unroll")                                                         \
    for (int s = 0; s < 4; s++)                                               \
      _Pragma("unroll")                                                       \
      for (int mt = 0; mt < 2; mt++)                                          \
        _Pragma("unroll")                                                     \
        for (int nt = 0; nt < 4; nt++)                                        \
          acc[mt][nt] = __builtin_amdgcn_mfma_f32_16x16x32_bf16(              \
              CUR[mt][s], Wf[nt][s], acc[mt][nt], 0,0,0);                     \
    __builtin_amdgcn_sched_barrier(0);                                        \
  }

  {
    int i = 0;
    for (; i + 2 <= NT; i += 2){
      CELL_BODY(i,   Aa, Ab, false);
      CELL_BODY(i+1, Ab, Aa, ((i+2==NT) && !(NT & 1)));
    }
    if (NT & 1) CELL_BODY(NT-1, Aa, Ab, true);
  }
#undef CELL_BODY
}

__device__ __forceinline__ void splitk_reduce(
    f32x4 acc[2][4], float* gbuf, int wm, int wk, int lane)
{
  const int rq = lane >> 4, cr = lane & 15;
  __syncthreads();   // all K-loop LDS reads + gll writes done -> safe to alias gbuf
  if (wk == 0){
    #pragma unroll
    for (int mt = 0; mt < 2; mt++)
      #pragma unroll
      for (int nt = 0; nt < 4; nt++)
        #pragma unroll
        for (int j = 0; j < 4; j++)
          gbuf[(wm*32 + mt*16 + rq*4 + j)*64 + nt*16 + cr] = acc[mt][nt][j];
  }
  __syncthreads();
  if (wk == 1){
    #pragma unroll
    for (int mt = 0; mt < 2; mt++)
      #pragma unroll
      for (int nt = 0; nt < 4; nt++)
        #pragma unroll
        for (int j = 0; j < 4; j++)
          gbuf[(wm*32 + mt*16 + rq*4 + j)*64 + nt*16 + cr] += acc[mt][nt][j];
  }
  __syncthreads();
}

// ---- LSTM cell phase: GEMM + split-K reduce + fused gate pointwise ----
template<int K, int KH, bool WTANH>
__device__ void cell_phase(
    const bf16* __restrict__ Acat, const bf16* __restrict__ Wr,
    const float* __restrict__ biasr, float* __restrict__ cst,
    bf16* __restrict__ dstA, int ldA, bf16* __restrict__ dstB, int ldB,
    char* smem, int m0, int n0, int wm, int wk, int lane, int tid)
{
  f32x4 acc[2][4] = {};
  gemm_tile64<K, KH>(Acat, Wr, smem, m0, n0, wm, wk, lane, acc);
  float* gbuf = (float*)smem;             // aliases stage buffers (dead now)
  splitk_reduce(acc, gbuf, wm, wk, lane);

  #pragma unroll
  for (int e = 0; e < 4; e++){
    int idx = e*256 + tid;                // 64 rows x 16 cols
    int r = idx >> 4, cl = idx & 15;
    f32x4 g  = *(const f32x4*)&gbuf[r*64 + cl*4];
    f32x4 bi = *(const f32x4*)&biasr[n0 + cl*4];
    int m = m0 + r;
    int col = (n0 >> 2) + cl;             // ntile*16 + cl
    float gi = g[0] + bi[0];
    float gf = g[1] + bi[1];
    float gg = g[2] + bi[2];
    float go = g[3] + bi[3];
    float cold = cst[m*HH + col];
    float cn = sigmoidf_(gf)*cold + sigmoidf_(gi)*tanhf(gg);
    float hn = sigmoidf_(go)*tanhf(cn);
    cst[m*HH + col] = cn;
    dstA[(size_t)m*ldA + col] = __float2bfloat16(hn);
    dstB[(size_t)m*ldB + col] = __float2bfloat16(WTANH ? tanhf(hn) : hn);
  }
}

// ---- dec phase: blocks 0..47, GEMM 64x64xK1024 + diffusion epilogue ----
__device__ void dec_phase(
    const bf16* __restrict__ th, const bf16* __restrict__ Wl,
    const float* __restrict__ alphas, const float* __restrict__ betas,
    const float* __restrict__ barals, const float* __restrict__ snoise,
    float* __restrict__ prev, float* __restrict__ out, bf16* __restrict__ xnext,
    char* smem, int m0, int n0, int wm, int wk, int lane, int tid, int t)
{
  f32x4 acc[2][4] = {};
  gemm_tile64<HH, 512>(th, Wl, smem, m0, n0, wm, wk, lane, acc);
  float* gbuf = (float*)smem;
  splitk_reduce(acc, gbuf, wm, wk, lane);

  const int idxs = SS - t;
  float a = alphas[idxs], ba = barals[idxs], be = betas[idxs];
  float coef = (1.0f - a) / sqrtf(1.0f - ba);
  float isq  = 1.0f / sqrtf(a);
  float nf = (t+1 < SS) ? sqrtf(be) : 0.0f;
  float* outp = out + (size_t)(SS-1-t) * (BB*X0);

  #pragma unroll
  for (int e = 0; e < 16; e++){
    int idx = e*256 + tid;                // 64 rows x 64 cols
    int r = idx >> 6, c = idx & 63;
    int m = m0 + r, n = n0 + c;
    float d = gbuf[r*64 + c];
    float pv = prev[m*X0 + n];
    float dec = (pv - coef*d)*isq + nf*snoise[t*BB + m];
    outp[m*X0 + n] = dec;
    prev[m*X0 + n] = dec;
    xnext[(size_t)m*K1 + n] = __float2bfloat16(dec);
  }
}

struct PersistArgs {
  const bf16* W0r; const bf16* W1r; const bf16* Wl;
  const float* bias0; const float* bias1;
  float* c0; float* c1;
  bf16* xcat0; bf16* xcat1; bf16* x2_0; bf16* x2_1; bf16* th;
  const float* alphas; const float* betas; const float* barals; const float* snoise;
  float* prev; float* out;
  unsigned* bar;
};

// =====================================================================
// persistent kernel: all 99 steps, grid 256 x 256 thr, manual grid barrier.
// 256 blocks = 256 CUs, 64KB LDS (2 blocks/CU capacity) -> all co-resident.
// =====================================================================
__global__ __launch_bounds__(256, 1) void persist(PersistArgs P)
{
  __shared__ __align__(16) char smem[65536];

  const int tid = threadIdx.x;
  const int wave = tid >> 6, lane = tid & 63;
  const int wm = wave & 1, wk = wave >> 1;

  const int bid = blockIdx.x;
  const int xcd = bid & 7, within = bid >> 3;
  const int ntile = xcd * 8 + (within & 7);
  const int mtile = within >> 3;            // 0..3
  const int m0 = mtile * 64;
  const int n0 = ntile * 64;

  const int dmt = bid / 12, dnt = bid % 12; // dec mapping, active if bid<48

  for (int t = 1; t < SS; t++){
    bf16* xc  = (t & 1) ? P.xcat1 : P.xcat0;
    bf16* xn  = (t & 1) ? P.xcat0 : P.xcat1;
    bf16* x2c = (t & 1) ? P.x2_1 : P.x2_0;
    bf16* x2n = (t & 1) ? P.x2_0 : P.x2_1;

    cell_phase<K1, 896, false>(xc, P.W0r, P.bias0, P.c0, x2c, K2, xn + X0, K1,
                               smem, m0, n0, wm, wk, lane, tid);
    grid_barrier(P.bar, tid, 256);
    cell_phase<K2, 1024, true>(x2c, P.W1r, P.bias1, P.c1, x2n + HH, K2, P.th, HH,
                               smem, m0, n0, wm, wk, lane, tid);
    grid_barrier(P.bar, tid, 256);
    if (bid < 48)
      dec_phase(P.th, P.Wl, P.alphas, P.betas, P.barals, P.snoise,
                P.prev, P.out, xn, smem, dmt*64, dnt*64, wm, wk, lane, tid, t);
    grid_barrier(P.bar, tid, 256);
  }
}

// =====================================================================
// setup-phase helpers (unchanged)
// =====================================================================
__device__ __forceinline__ void gemm32x32(const bf16* __restrict__ A, int lda,
                                          const bf16* __restrict__ W, int ldw,
                                          int m0, int wr0, int K,
                                          f32x4 acc[2][2], int lane)
{
  int r  = lane & 15;
  int kq = lane >> 4;
  const bf16* a0 = A + (size_t)(m0 + r)      * lda + kq*8;
  const bf16* a1 = A + (size_t)(m0 + 16 + r) * lda + kq*8;
  const bf16* b0 = W + (size_t)(wr0 + r)      * ldw + kq*8;
  const bf16* b1 = W + (size_t)(wr0 + 16 + r) * ldw + kq*8;
  for (int kk = 0; kk < K; kk += 32) {
    bf16x8 av0 = *(const bf16x8*)(a0 + kk);
    bf16x8 av1 = *(const bf16x8*)(a1 + kk);
    bf16x8 bv0 = *(const bf16x8*)(b0 + kk);
    bf16x8 bv1 = *(const bf16x8*)(b1 + kk);
    acc[0][0] = __builtin_amdgcn_mfma_f32_16x16x32_bf16(av0, bv0, acc[0][0], 0,0,0);
    acc[0][1] = __builtin_amdgcn_mfma_f32_16x16x32_bf16(av0, bv1, acc[0][1], 0,0,0);
    acc[1][0] = __builtin_amdgcn_mfma_f32_16x16x32_bf16(av1, bv0, acc[1][0], 0,0,0);
    acc[1][1] = __builtin_amdgcn_mfma_f32_16x16x32_bf16(av1, bv1, acc[1][1], 0,0,0);
  }
}

template<int EPI>
__global__ __launch_bounds__(256) void rgemm_kernel(
    const bf16* __restrict__ A, const bf16* __restrict__ W,
    const float* __restrict__ bias, const float* __restrict__ resid,
    bf16* __restrict__ d1, int ld1, bf16* __restrict__ d2, int ld2,
    float* __restrict__ f1, float* __restrict__ f2)
{
  int tid=threadIdx.x, wave=tid>>6, lane=tid&63;
  int m0 = blockIdx.x*32;
  int n0 = (blockIdx.y*4+wave)*32;
  f32x4 acc[2][2] = {};
  gemm32x32(A, HH, W, HH, m0, n0, HH, acc, lane);
  int cr=lane&15, rq=lane>>4;
  for (int r=0;r<2;r++) for (int c=0;c<2;c++) for (int j=0;j<4;j++) {
    int m = m0 + r*16+rq*4+j, n = n0 + c*16+cr;
    float v = acc[r][c][j] + bias[n];
    if (EPI==0) {
      float h = fmaxf(v,0.f) + resid[m*HH+n];
      d1[(size_t)m*ld1+n] = __float2bfloat16(h);
    } else if (EPI==1) {
      float tv = tanhf(v);
      if (n < HH) d1[(size_t)m*ld1+n] = __float2bfloat16(tv);
      else        d2[(size_t)m*ld2 + (n-HH)] = __float2bfloat16(tv);
    } else {
      float tv = tanhf(v);
      if (n < HH) f1[m*HH+n] = tv;
      else        f2[m*HH + (n-HH)] = tv;
    }
  }
}

// W rows interleaved: n' = col*4 + gate
__global__ void prep_w0_kernel(const float* __restrict__ Wih0, const float* __restrict__ Whh0,
                               bf16* __restrict__ W0r){
  int i = blockIdx.x*256 + threadIdx.x;
  if (i >= NG*K1) return;
  int np = i / K1, k = i % K1;
  int col = np >> 2, g = np & 3;
  int srow = g*HH + col;
  float v = (k < X0) ? Wih0[srow*X0 + k] : Whh0[srow*HH + (k - X0)];
  W0r[i] = __float2bfloat16(v);
}
__global__ void prep_w1_kernel(const float* __restrict__ Wih1, const float* __restrict__ Whh1,
                               bf16* __restrict__ W1r){
  int i = blockIdx.x*256 + threadIdx.x;
  if (i >= NG*K2) return;
  int np = i / K2, k = i % K2;
  int col = np >> 2, g = np & 3;
  int srow = g*HH + col;
  float v = (k < HH) ? Wih1[srow*HH + k] : Whh1[srow*HH + (k - HH)];
  W1r[i] = __float2bfloat16(v);
}
__global__ void cvt_kernel(const float* __restrict__ s, bf16* __restrict__ d, int n){
  int i = blockIdx.x*256 + threadIdx.x;
  if (i < n) d[i] = __float2bfloat16(s[i]);
}
__global__ void prep_bias_kernel(const float* bih0, const float* bhh0,
                                 const float* bih1, const float* bhh1,
                                 float* b0, float* b1, unsigned* bar){
  int i = blockIdx.x*256 + threadIdx.x;
  if (i < NG){
    int col = i >> 2, g = i & 3;
    int s = g*HH + col;
    b0[i] = bih0[s] + bhh0[s];
    b1[i] = bih1[s] + bhh1[s];
  }
  if (i < 64) bar[i] = 0u;   // zero barrier state (cnt, gen) every call
}
__global__ void init_x_kernel(const float* __restrict__ z, float* __restrict__ prev,
                              bf16* __restrict__ xcat1, float* __restrict__ out){
  int i = blockIdx.x*256 + threadIdx.x;
  if (i >= BB*X0) return;
  int m = i / X0, col = i % X0;
  int l = col / OUTD, d = col % OUTD;
  float v = z[(size_t)(m*LL + l)*DD + d];
  prev[i] = v;
  out[(size_t)(SS-1)*BB*X0 + i] = v;
  xcat1[(size_t)m*K1 + col] = __float2bfloat16(v);
}
__global__ void r1_kernel(const float* __restrict__ n0,
    const float* __restrict__ A1a, const float* __restrict__ b1a,
    const float* __restrict__ A1b, const float* __restrict__ b1b,
    float* __restrict__ h1fa, bf16* __restrict__ h1ba,
    float* __restrict__ h1fb, bf16* __restrict__ h1bb){
  int gid = blockIdx.x*256 + threadIdx.x;
  if (gid >= BB*2*HH) return;
  int m = gid >> 11;
  int col = gid & 2047;
  const float* A1; const float* b1; float* hf; bf16* hb; int c;
  if (col < HH){ A1=A1a; b1=b1a; hf=h1fa; hb=h1ba; c=col; }
  else         { A1=A1b; b1=b1b; hf=h1fb; hb=h1bb; c=col-HH; }
  float v = b1[c];
  for (int d=0; d<DD; d++) v += n0[m*DD + d] * A1[c*DD + d];
  v = fmaxf(v, 0.f);
  hf[m*HH + c] = v;
  hb[m*HH + c] = __float2bfloat16(v);
}

static inline size_t alup(size_t x){ return (x + 255) & ~(size_t)255; }

extern "C" void kernel_launch(void* const* d_in, const int* in_sizes, int n_in,
                              void* d_out, int out_size, void* d_ws, size_t ws_size,
                              hipStream_t stream) {
  const float* z      = (const float*)d_in[4];
  const float* n0     = (const float*)d_in[5];
  const float* snoise = (const float*)d_in[6];
  const float* alphas = (const float*)d_in[7];
  const float* betas  = (const float*)d_in[8];
  const float* barals = (const float*)d_in[9];
  const float* A1a = (const float*)d_in[10]; const float* b1a = (const float*)d_in[11];
  const float* A2a = (const float*)d_in[12]; const float* b2a = (const float*)d_in[13];
  const float* A3a = (const float*)d_in[14]; const float* b3a = (const float*)d_in[15];
  const float* A1b = (const float*)d_in[16]; const float* b1b = (const float*)d_in[17];
  const float* A2b = (const float*)d_in[18]; const float* b2b = (const float*)d_in[19];
  const float* A3b = (const float*)d_in[20]; const float* b3b = (const float*)d_in[21];
  const float* Wih0 = (const float*)d_in[22]; const float* Whh0 = (const float*)d_in[23];
  const float* bih0 = (const float*)d_in[24]; const float* bhh0 = (const float*)d_in[25];
  const float* Wih1 = (const float*)d_in[26]; const float* Whh1 = (const float*)d_in[27];
  const float* bih1 = (const float*)d_in[28]; const float* bhh1 = (const float*)d_in[29];
  const float* Wlin = (const float*)d_in[30];
  float* out = (float*)d_out;

  char* p = (char*)d_ws;
  size_t off = 0;
  auto take = [&](size_t bytes)->char*{ char* r = p + off; off = alup(off + bytes); return r; };
  bf16* W0cat = (bf16*)take((size_t)NG*K1*2);
  bf16* W1cat = (bf16*)take((size_t)NG*K2*2);
  bf16* WlinB = (bf16*)take((size_t)X0*HH*2);
  bf16* A2aB  = (bf16*)take((size_t)HH*HH*2);
  bf16* A2bB  = (bf16*)take((size_t)HH*HH*2);
  bf16* A3aB  = (bf16*)take((size_t)2*HH*HH*2);
  bf16* A3bB  = (bf16*)take((size_t)2*HH*HH*2);
  float* bias0 = (float*)take(NG*4);
  float* bias1 = (float*)take(NG*4);
  bf16* xcat0 = (bf16*)take((size_t)BB*K1*2);
  bf16* xcat1 = (bf16*)take((size_t)BB*K1*2);
  bf16* x2_0  = (bf16*)take((size_t)BB*K2*2);
  bf16* x2_1  = (bf16*)take((size_t)BB*K2*2);
  bf16* th    = (bf16*)take((size_t)BB*HH*2);
  float* c0   = (float*)take((size_t)BB*HH*4);
  float* c1   = (float*)take((size_t)BB*HH*4);
  float* prev = (float*)take((size_t)BB*X0*4);
  float* h1fa = (float*)take((size_t)BB*HH*4);
  float* h1fb = (float*)take((size_t)BB*HH*4);
  bf16* h1ba  = (bf16*)take((size_t)BB*HH*2);
  bf16* h1bb  = (bf16*)take((size_t)BB*HH*2);
  bf16* h2ba  = (bf16*)take((size_t)BB*HH*2);
  bf16* h2bb  = (bf16*)take((size_t)BB*HH*2);
  unsigned* bar = (unsigned*)take(256);
  (void)ws_size; (void)in_sizes; (void)n_in; (void)out_size;

  prep_w0_kernel<<<(NG*K1+255)/256, 256, 0, stream>>>(Wih0, Whh0, W0cat);
  prep_w1_kernel<<<(NG*K2+255)/256, 256, 0, stream>>>(Wih1, Whh1, W1cat);
  cvt_kernel<<<(X0*HH+255)/256, 256, 0, stream>>>(Wlin, WlinB, X0*HH);
  cvt_kernel<<<(HH*HH+255)/256, 256, 0, stream>>>(A2a, A2aB, HH*HH);
  cvt_kernel<<<(HH*HH+255)/256, 256, 0, stream>>>(A2b, A2bB, HH*HH);
  cvt_kernel<<<(2*HH*HH+255)/256, 256, 0, stream>>>(A3a, A3aB, 2*HH*HH);
  cvt_kernel<<<(2*HH*HH+255)/256, 256, 0, stream>>>(A3b, A3bB, 2*HH*HH);
  prep_bias_kernel<<<(NG+255)/256, 256, 0, stream>>>(bih0, bhh0, bih1, bhh1, bias0, bias1, bar);
  init_x_kernel<<<(BB*X0+255)/256, 256, 0, stream>>>(z, prev, xcat1, out);
  r1_kernel<<<(BB*2*HH+255)/256, 256, 0, stream>>>(n0, A1a, b1a, A1b, b1b, h1fa, h1ba, h1fb, h1bb);
  rgemm_kernel<0><<<dim3(8,8), 256, 0, stream>>>(h1ba, A2aB, b2a, h1fa, h2ba, HH, nullptr, 0, nullptr, nullptr);
  rgemm_kernel<0><<<dim3(8,8), 256, 0, stream>>>(h1bb, A2bB, b2b, h1fb, h2bb, HH, nullptr, 0, nullptr, nullptr);
  rgemm_kernel<1><<<dim3(8,16), 256, 0, stream>>>(h2ba, A3aB, b3a, nullptr, xcat1 + X0, K1, x2_1 + HH, K2, nullptr, nullptr);
  rgemm_kernel<2><<<dim3(8,16), 256, 0, stream>>>(h2bb, A3bB, b3b, nullptr, nullptr, 0, nullptr, 0, c0, c1);

  PersistArgs pa;
  pa.W0r = W0cat; pa.W1r = W1cat; pa.Wl = WlinB;
  pa.bias0 = bias0; pa.bias1 = bias1;
  pa.c0 = c0; pa.c1 = c1;
  pa.xcat0 = xcat0; pa.xcat1 = xcat1; pa.x2_0 = x2_0; pa.x2_1 = x2_1; pa.th = th;
  pa.alphas = alphas; pa.betas = betas; pa.barals = barals; pa.snoise = snoise;
  pa.prev = prev; pa.out = out;
  pa.bar = bar;
  persist<<<256, 256, 0, stream>>>(pa);
}

// Round 8
// 7074.487 us; speedup vs baseline: 3.4165x; 1.3596x over previous
//
#include <hip/hip_runtime.h>
#include <hip/hip_bf16.h>
#include <math.h>

#define BB 256
#define LL 256
#define DD 4
#define HH 1024
#define SS 100
#define OUTD 3
#define X0 768          /* L*OUT */
#define K1 1792         /* 768 + 1024 */
#define K2 2048
#define NG 4096

typedef __attribute__((ext_vector_type(4))) float f32x4;
typedef __attribute__((ext_vector_type(8))) short bf16x8;
typedef __hip_bfloat16 bf16;

__device__ __forceinline__ float sigmoidf_(float x){ return 1.0f/(1.0f + __expf(-x)); }

__device__ __forceinline__ void gll16(const void* g, void* l){
  __builtin_amdgcn_global_load_lds((const __attribute__((address_space(1))) unsigned int*)g,
                                   (__attribute__((address_space(3))) unsigned int*)l, 16, 0, 0);
}

// ---- device-scope (L2-bypassing) activation access: sc0 sc1 ----
// Cross-block activations live in L3 only; L2s never cache them -> no
// buffer_inv needed anywhere -> weights stay L2-resident all 99 steps.
__device__ __forceinline__ bf16x8 gload_cg(const void* p){
  bf16x8 r;
  asm volatile("global_load_dwordx4 %0, %1, off sc0 sc1" : "=v"(r) : "v"(p));
  return r;
}
__device__ __forceinline__ void gstore_cg2(void* p, unsigned short v){
  asm volatile("global_store_short %0, %1, off sc0 sc1" :: "v"(p), "v"(v) : "memory");
}

// ---- two-level grid barrier, ALL-RELAXED (no cache maintenance) ----
// bar lines (128B apart): grp[0..7] at bar+g*32, root at bar+256, gen at bar+288.
// Correctness: every wave drains vmcnt(0) before s_barrier -> all bypass
// stores are acked at L3 before tid0's arrival RMW. Reset->flip ordering is
// enforced by the implicit vmcnt(0) the compiler emits to read each RMW result.
__device__ __forceinline__ void grid_barrier(unsigned* bar, int tid, int bid){
  asm volatile("s_waitcnt vmcnt(0)" ::: "memory");
  __syncthreads();
  if (tid == 0){
    unsigned* grp  = bar + (bid & 7) * 32;
    unsigned* root = bar + 256;
    unsigned* gen  = bar + 288;
    unsigned g = __hip_atomic_load(gen, __ATOMIC_RELAXED, __HIP_MEMORY_SCOPE_AGENT);
    unsigned a = __hip_atomic_fetch_add(grp, 1u, __ATOMIC_RELAXED, __HIP_MEMORY_SCOPE_AGENT);
    bool flip = false;
    if (a == 31u){
      __hip_atomic_store(grp, 0u, __ATOMIC_RELAXED, __HIP_MEMORY_SCOPE_AGENT);
      unsigned r = __hip_atomic_fetch_add(root, 1u, __ATOMIC_RELAXED, __HIP_MEMORY_SCOPE_AGENT);
      if (r == 7u){
        __hip_atomic_store(root, 0u, __ATOMIC_RELAXED, __HIP_MEMORY_SCOPE_AGENT);
        __hip_atomic_store(gen, g + 1u, __ATOMIC_RELAXED, __HIP_MEMORY_SCOPE_AGENT);
        flip = true;
      }
    }
    if (!flip){
      while (__hip_atomic_load(gen, __ATOMIC_RELAXED, __HIP_MEMORY_SCOPE_AGENT) == g)
        __builtin_amdgcn_s_sleep(4);
    }
  }
  __syncthreads();
}

// =====================================================================
// 64x64-tile GEMM core. Block: 4 waves = (2 m-halves wm) x (2 K-halves wk).
// W staged to LDS via gll (NORMAL cached path -> L2-resident weights);
// A (activation) loaded DIRECT global->reg via sc0sc1 bypass loads.
// Per body per wave: 8 gll + 8 bypass A-loads = 16 -> vmcnt(16) counting.
// =====================================================================
template<int K, int KH>
__device__ __forceinline__ void gemm_tile64(
    const bf16* __restrict__ Acat, const bf16* __restrict__ Wr,
    char* __restrict__ smem, int m0, int n0, int wm, int wk, int lane,
    f32x4 acc[2][4])
{
  constexpr int NT = KH / 128;
  const int lr = lane & 15, kq16 = lane >> 4;

  const char* srcW[8];
  int ldsoff[8];
  #pragma unroll
  for (int j = 0; j < 8; j++){
    int c = wm*8 + j;
    int row = c*4 + (lane >> 4);
    int slot = (lane & 15) ^ (row & 7);
    srcW[j] = (const char*)(Wr + (size_t)(n0 + row) * K + wk * KH) + slot * 16;
    ldsoff[j] = c * 1024;
  }
  const char* aptr[2];
  #pragma unroll
  for (int mt = 0; mt < 2; mt++)
    aptr[mt] = (const char*)(Acat + (size_t)(m0 + wm*32 + mt*16 + lr) * K + wk * KH) + kq16 * 16;

  int woff[4][4];
  #pragma unroll
  for (int nt = 0; nt < 4; nt++)
    #pragma unroll
    for (int s = 0; s < 4; s++){
      int row = nt*16 + lr;
      woff[nt][s] = row*256 + (((s*4 + kq16) ^ (row & 7)) << 4);
    }

  bf16x8 Aa[2][4], Ab[2][4];
  {
    char* db = smem + wk*32768;
    #pragma unroll
    for (int j = 0; j < 8; j++) gll16(srcW[j], db + ldsoff[j]);
    __builtin_amdgcn_sched_barrier(0);
    #pragma unroll
    for (int mt = 0; mt < 2; mt++)
      #pragma unroll
      for (int s = 0; s < 4; s++)
        Aa[mt][s] = gload_cg(aptr[mt] + s*64);
  }

#define CELL_BODY(I, CUR, NXT, LAST)                                          \
  {                                                                           \
    __builtin_amdgcn_s_barrier();                                             \
    if (!(LAST)) {                                                            \
      char* db = smem + wk*32768 + (((I)+1)&1)*16384;                         \
      _Pragma("unroll")                                                       \
      for (int j = 0; j < 8; j++)                                             \
        gll16(srcW[j] + (size_t)((I)+1)*256, db + ldsoff[j]);                 \
      __builtin_amdgcn_sched_barrier(0);                                      \
      _Pragma("unroll")                                                       \
      for (int mt = 0; mt < 2; mt++)                                          \
        _Pragma("unroll")                                                     \
        for (int s = 0; s < 4; s++)                                           \
          NXT[mt][s] = gload_cg(aptr[mt] + (size_t)((I)+1)*256 + s*64);       \
      asm volatile("s_waitcnt vmcnt(16)" ::: "memory");                       \
    } else {                                                                  \
      asm volatile("s_waitcnt vmcnt(0)" ::: "memory");                        \
    }                                                                         \
    __builtin_amdgcn_s_barrier();                                             \
    __builtin_amdgcn_sched_barrier(0);                                        \
    const char* wb = smem + wk*32768 + ((I)&1)*16384;                         \
    bf16x8 Wf[4][4];                                                          \
    _Pragma("unroll")                                                         \
    for (int nt = 0; nt < 4; nt++)                                            \
      _Pragma("unroll")                                                       \
      for (int s = 0; s < 4; s++)                                             \
        Wf[nt][s] = *(const bf16x8*)(wb + woff[nt][s]);                       \
    _Pragma("unroll")                                                         \
    for (int s = 0; s < 4; s++)                                               \
      _Pragma("unroll")                                                       \
      for (int mt = 0; mt < 2; mt++)                                          \
        _Pragma("unroll")                                                     \
        for (int nt = 0; nt < 4; nt++)                                        \
          acc[mt][nt] = __builtin_amdgcn_mfma_f32_16x16x32_bf16(              \
              CUR[mt][s], Wf[nt][s], acc[mt][nt], 0,0,0);                     \
    __builtin_amdgcn_sched_barrier(0);                                        \
  }

  {
    int i = 0;
    for (; i + 2 <= NT; i += 2){
      CELL_BODY(i,   Aa, Ab, false);
      CELL_BODY(i+1, Ab, Aa, ((i+2==NT) && !(NT & 1)));
    }
    if (NT & 1) CELL_BODY(NT-1, Aa, Ab, true);
  }
#undef CELL_BODY
}

__device__ __forceinline__ void splitk_reduce(
    f32x4 acc[2][4], float* gbuf, int wm, int wk, int lane)
{
  const int rq = lane >> 4, cr = lane & 15;
  __syncthreads();   // all K-loop LDS reads + gll writes done -> safe to alias gbuf
  if (wk == 0){
    #pragma unroll
    for (int mt = 0; mt < 2; mt++)
      #pragma unroll
      for (int nt = 0; nt < 4; nt++)
        #pragma unroll
        for (int j = 0; j < 4; j++)
          gbuf[(wm*32 + mt*16 + rq*4 + j)*64 + nt*16 + cr] = acc[mt][nt][j];
  }
  __syncthreads();
  if (wk == 1){
    #pragma unroll
    for (int mt = 0; mt < 2; mt++)
      #pragma unroll
      for (int nt = 0; nt < 4; nt++)
        #pragma unroll
        for (int j = 0; j < 4; j++)
          gbuf[(wm*32 + mt*16 + rq*4 + j)*64 + nt*16 + cr] += acc[mt][nt][j];
  }
  __syncthreads();
}

// ---- LSTM cell phase: GEMM + split-K reduce + fused gate pointwise ----
// h/th writes are bypass stores (cross-block); c-state normal (block-local).
template<int K, int KH, bool WTANH>
__device__ void cell_phase(
    const bf16* __restrict__ Acat, const bf16* __restrict__ Wr,
    const float* __restrict__ biasr, float* __restrict__ cst,
    bf16* __restrict__ dstA, int ldA, bf16* __restrict__ dstB, int ldB,
    char* smem, int m0, int n0, int wm, int wk, int lane, int tid)
{
  f32x4 acc[2][4] = {};
  gemm_tile64<K, KH>(Acat, Wr, smem, m0, n0, wm, wk, lane, acc);
  float* gbuf = (float*)smem;             // aliases stage buffers (dead now)
  splitk_reduce(acc, gbuf, wm, wk, lane);

  #pragma unroll
  for (int e = 0; e < 4; e++){
    int idx = e*256 + tid;                // 64 rows x 16 cols
    int r = idx >> 4, cl = idx & 15;
    f32x4 g  = *(const f32x4*)&gbuf[r*64 + cl*4];
    f32x4 bi = *(const f32x4*)&biasr[n0 + cl*4];
    int m = m0 + r;
    int col = (n0 >> 2) + cl;             // ntile*16 + cl
    float gi = g[0] + bi[0];
    float gf = g[1] + bi[1];
    float gg = g[2] + bi[2];
    float go = g[3] + bi[3];
    float cold = cst[m*HH + col];
    float cn = sigmoidf_(gf)*cold + sigmoidf_(gi)*tanhf(gg);
    float hn = sigmoidf_(go)*tanhf(cn);
    cst[m*HH + col] = cn;
    bf16 hb = __float2bfloat16(hn);
    gstore_cg2(&dstA[(size_t)m*ldA + col], *(unsigned short*)&hb);
    bf16 tb = __float2bfloat16(WTANH ? tanhf(hn) : hn);
    gstore_cg2(&dstB[(size_t)m*ldB + col], *(unsigned short*)&tb);
  }
}

// ---- dec phase: blocks 0..47, GEMM 64x64xK1024 + diffusion epilogue ----
__device__ void dec_phase(
    const bf16* __restrict__ th, const bf16* __restrict__ Wl,
    const float* __restrict__ alphas, const float* __restrict__ betas,
    const float* __restrict__ barals, const float* __restrict__ snoise,
    float* __restrict__ prev, float* __restrict__ out, bf16* __restrict__ xnext,
    char* smem, int m0, int n0, int wm, int wk, int lane, int tid, int t)
{
  f32x4 acc[2][4] = {};
  gemm_tile64<HH, 512>(th, Wl, smem, m0, n0, wm, wk, lane, acc);
  float* gbuf = (float*)smem;
  splitk_reduce(acc, gbuf, wm, wk, lane);

  const int idxs = SS - t;
  float a = alphas[idxs], ba = barals[idxs], be = betas[idxs];
  float coef = (1.0f - a) / sqrtf(1.0f - ba);
  float isq  = 1.0f / sqrtf(a);
  float nf = (t+1 < SS) ? sqrtf(be) : 0.0f;
  float* outp = out + (size_t)(SS-1-t) * (BB*X0);

  #pragma unroll
  for (int e = 0; e < 16; e++){
    int idx = e*256 + tid;                // 64 rows x 64 cols
    int r = idx >> 6, c = idx & 63;
    int m = m0 + r, n = n0 + c;
    float d = gbuf[r*64 + c];
    float pv = prev[m*X0 + n];
    float dec = (pv - coef*d)*isq + nf*snoise[t*BB + m];
    outp[m*X0 + n] = dec;                 // normal (nobody re-reads)
    prev[m*X0 + n] = dec;                 // normal (block-local)
    bf16 xb = __float2bfloat16(dec);
    gstore_cg2(&xnext[(size_t)m*K1 + n], *(unsigned short*)&xb);  // cross-block
  }
}

struct PersistArgs {
  const bf16* W0r; const bf16* W1r; const bf16* Wl;
  const float* bias0; const float* bias1;
  float* c0; float* c1;
  bf16* xcat0; bf16* xcat1; bf16* x2_0; bf16* x2_1; bf16* th;
  const float* alphas; const float* betas; const float* barals; const float* snoise;
  float* prev; float* out;
  unsigned* bar;
};

// =====================================================================
// persistent kernel: all 99 steps, grid 256 x 256 thr, relaxed tree barrier.
// 256 blocks = 256 CUs, 64KB LDS -> all co-resident.
// =====================================================================
__global__ __launch_bounds__(256, 1) void persist(PersistArgs P)
{
  __shared__ __align__(16) char smem[65536];

  const int tid = threadIdx.x;
  const int wave = tid >> 6, lane = tid & 63;
  const int wm = wave & 1, wk = wave >> 1;

  const int bid = blockIdx.x;
  const int xcd = bid & 7, within = bid >> 3;
  const int ntile = xcd * 8 + (within & 7);
  const int mtile = within >> 3;            // 0..3
  const int m0 = mtile * 64;
  const int n0 = ntile * 64;

  const int dmt = bid / 12, dnt = bid % 12; // dec mapping, active if bid<48

  for (int t = 1; t < SS; t++){
    bf16* xc  = (t & 1) ? P.xcat1 : P.xcat0;
    bf16* xn  = (t & 1) ? P.xcat0 : P.xcat1;
    bf16* x2c = (t & 1) ? P.x2_1 : P.x2_0;
    bf16* x2n = (t & 1) ? P.x2_0 : P.x2_1;

    cell_phase<K1, 896, false>(xc, P.W0r, P.bias0, P.c0, x2c, K2, xn + X0, K1,
                               smem, m0, n0, wm, wk, lane, tid);
    grid_barrier(P.bar, tid, bid);
    cell_phase<K2, 1024, true>(x2c, P.W1r, P.bias1, P.c1, x2n + HH, K2, P.th, HH,
                               smem, m0, n0, wm, wk, lane, tid);
    grid_barrier(P.bar, tid, bid);
    if (bid < 48)
      dec_phase(P.th, P.Wl, P.alphas, P.betas, P.barals, P.snoise,
                P.prev, P.out, xn, smem, dmt*64, dnt*64, wm, wk, lane, tid, t);
    grid_barrier(P.bar, tid, bid);
  }
}

// =====================================================================
// setup-phase helpers (unchanged)
// =====================================================================
__device__ __forceinline__ void gemm32x32(const bf16* __restrict__ A, int lda,
                                          const bf16* __restrict__ W, int ldw,
                                          int m0, int wr0, int K,
                                          f32x4 acc[2][2], int lane)
{
  int r  = lane & 15;
  int kq = lane >> 4;
  const bf16* a0 = A + (size_t)(m0 + r)      * lda + kq*8;
  const bf16* a1 = A + (size_t)(m0 + 16 + r) * lda + kq*8;
  const bf16* b0 = W + (size_t)(wr0 + r)      * ldw + kq*8;
  const bf16* b1 = W + (size_t)(wr0 + 16 + r) * ldw + kq*8;
  for (int kk = 0; kk < K; kk += 32) {
    bf16x8 av0 = *(const bf16x8*)(a0 + kk);
    bf16x8 av1 = *(const bf16x8*)(a1 + kk);
    bf16x8 bv0 = *(const bf16x8*)(b0 + kk);
    bf16x8 bv1 = *(const bf16x8*)(b1 + kk);
    acc[0][0] = __builtin_amdgcn_mfma_f32_16x16x32_bf16(av0, bv0, acc[0][0], 0,0,0);
    acc[0][1] = __builtin_amdgcn_mfma_f32_16x16x32_bf16(av0, bv1, acc[0][1], 0,0,0);
    acc[1][0] = __builtin_amdgcn_mfma_f32_16x16x32_bf16(av1, bv0, acc[1][0], 0,0,0);
    acc[1][1] = __builtin_amdgcn_mfma_f32_16x16x32_bf16(av1, bv1, acc[1][1], 0,0,0);
  }
}

template<int EPI>
__global__ __launch_bounds__(256) void rgemm_kernel(
    const bf16* __restrict__ A, const bf16* __restrict__ W,
    const float* __restrict__ bias, const float* __restrict__ resid,
    bf16* __restrict__ d1, int ld1, bf16* __restrict__ d2, int ld2,
    float* __restrict__ f1, float* __restrict__ f2)
{
  int tid=threadIdx.x, wave=tid>>6, lane=tid&63;
  int m0 = blockIdx.x*32;
  int n0 = (blockIdx.y*4+wave)*32;
  f32x4 acc[2][2] = {};
  gemm32x32(A, HH, W, HH, m0, n0, HH, acc, lane);
  int cr=lane&15, rq=lane>>4;
  for (int r=0;r<2;r++) for (int c=0;c<2;c++) for (int j=0;j<4;j++) {
    int m = m0 + r*16+rq*4+j, n = n0 + c*16+cr;
    float v = acc[r][c][j] + bias[n];
    if (EPI==0) {
      float h = fmaxf(v,0.f) + resid[m*HH+n];
      d1[(size_t)m*ld1+n] = __float2bfloat16(h);
    } else if (EPI==1) {
      float tv = tanhf(v);
      if (n < HH) d1[(size_t)m*ld1+n] = __float2bfloat16(tv);
      else        d2[(size_t)m*ld2 + (n-HH)] = __float2bfloat16(tv);
    } else {
      float tv = tanhf(v);
      if (n < HH) f1[m*HH+n] = tv;
      else        f2[m*HH + (n-HH)] = tv;
    }
  }
}

// W rows interleaved: n' = col*4 + gate
__global__ void prep_w0_kernel(const float* __restrict__ Wih0, const float* __restrict__ Whh0,
                               bf16* __restrict__ W0r){
  int i = blockIdx.x*256 + threadIdx.x;
  if (i >= NG*K1) return;
  int np = i / K1, k = i % K1;
  int col = np >> 2, g = np & 3;
  int srow = g*HH + col;
  float v = (k < X0) ? Wih0[srow*X0 + k] : Whh0[srow*HH + (k - X0)];
  W0r[i] = __float2bfloat16(v);
}
__global__ void prep_w1_kernel(const float* __restrict__ Wih1, const float* __restrict__ Whh1,
                               bf16* __restrict__ W1r){
  int i = blockIdx.x*256 + threadIdx.x;
  if (i >= NG*K2) return;
  int np = i / K2, k = i % K2;
  int col = np >> 2, g = np & 3;
  int srow = g*HH + col;
  float v = (k < HH) ? Wih1[srow*HH + k] : Whh1[srow*HH + (k - HH)];
  W1r[i] = __float2bfloat16(v);
}
__global__ void cvt_kernel(const float* __restrict__ s, bf16* __restrict__ d, int n){
  int i = blockIdx.x*256 + threadIdx.x;
  if (i < n) d[i] = __float2bfloat16(s[i]);
}
__global__ void prep_bias_kernel(const float* bih0, const float* bhh0,
                                 const float* bih1, const float* bhh1,
                                 float* b0, float* b1, unsigned* bar){
  int i = blockIdx.x*256 + threadIdx.x;
  if (i < NG){
    int col = i >> 2, g = i & 3;
    int s = g*HH + col;
    b0[i] = bih0[s] + bhh0[s];
    b1[i] = bih1[s] + bhh1[s];
  }
  if (i < 512) bar[i] = 0u;   // zero barrier state every call (replay-safe)
}
__global__ void init_x_kernel(const float* __restrict__ z, float* __restrict__ prev,
                              bf16* __restrict__ xcat1, float* __restrict__ out){
  int i = blockIdx.x*256 + threadIdx.x;
  if (i >= BB*X0) return;
  int m = i / X0, col = i % X0;
  int l = col / OUTD, d = col % OUTD;
  float v = z[(size_t)(m*LL + l)*DD + d];
  prev[i] = v;
  out[(size_t)(SS-1)*BB*X0 + i] = v;
  xcat1[(size_t)m*K1 + col] = __float2bfloat16(v);
}
__global__ void r1_kernel(const float* __restrict__ n0,
    const float* __restrict__ A1a, const float* __restrict__ b1a,
    const float* __restrict__ A1b, const float* __restrict__ b1b,
    float* __restrict__ h1fa, bf16* __restrict__ h1ba,
    float* __restrict__ h1fb, bf16* __restrict__ h1bb){
  int gid = blockIdx.x*256 + threadIdx.x;
  if (gid >= BB*2*HH) return;
  int m = gid >> 11;
  int col = gid & 2047;
  const float* A1; const float* b1; float* hf; bf16* hb; int c;
  if (col < HH){ A1=A1a; b1=b1a; hf=h1fa; hb=h1ba; c=col; }
  else         { A1=A1b; b1=b1b; hf=h1fb; hb=h1bb; c=col-HH; }
  float v = b1[c];
  for (int d=0; d<DD; d++) v += n0[m*DD + d] * A1[c*DD + d];
  v = fmaxf(v, 0.f);
  hf[m*HH + c] = v;
  hb[m*HH + c] = __float2bfloat16(v);
}

static inline size_t alup(size_t x){ return (x + 255) & ~(size_t)255; }

extern "C" void kernel_launch(void* const* d_in, const int* in_sizes, int n_in,
                              void* d_out, int out_size, void* d_ws, size_t ws_size,
                              hipStream_t stream) {
  const float* z      = (const float*)d_in[4];
  const float* n0     = (const float*)d_in[5];
  const float* snoise = (const float*)d_in[6];
  const float* alphas = (const float*)d_in[7];
  const float* betas  = (const float*)d_in[8];
  const float* barals = (const float*)d_in[9];
  const float* A1a = (const float*)d_in[10]; const float* b1a = (const float*)d_in[11];
  const float* A2a = (const float*)d_in[12]; const float* b2a = (const float*)d_in[13];
  const float* A3a = (const float*)d_in[14]; const float* b3a = (const float*)d_in[15];
  const float* A1b = (const float*)d_in[16]; const float* b1b = (const float*)d_in[17];
  const float* A2b = (const float*)d_in[18]; const float* b2b = (const float*)d_in[19];
  const float* A3b = (const float*)d_in[20]; const float* b3b = (const float*)d_in[21];
  const float* Wih0 = (const float*)d_in[22]; const float* Whh0 = (const float*)d_in[23];
  const float* bih0 = (const float*)d_in[24]; const float* bhh0 = (const float*)d_in[25];
  const float* Wih1 = (const float*)d_in[26]; const float* Whh1 = (const float*)d_in[27];
  const float* bih1 = (const float*)d_in[28]; const float* bhh1 = (const float*)d_in[29];
  const float* Wlin = (const float*)d_in[30];
  float* out = (float*)d_out;

  char* p = (char*)d_ws;
  size_t off = 0;
  auto take = [&](size_t bytes)->char*{ char* r = p + off; off = alup(off + bytes); return r; };
  bf16* W0cat = (bf16*)take((size_t)NG*K1*2);
  bf16* W1cat = (bf16*)take((size_t)NG*K2*2);
  bf16* WlinB = (bf16*)take((size_t)X0*HH*2);
  bf16* A2aB  = (bf16*)take((size_t)HH*HH*2);
  bf16* A2bB  = (bf16*)take((size_t)HH*HH*2);
  bf16* A3aB  = (bf16*)take((size_t)2*HH*HH*2);
  bf16* A3bB  = (bf16*)take((size_t)2*HH*HH*2);
  float* bias0 = (float*)take(NG*4);
  float* bias1 = (float*)take(NG*4);
  bf16* xcat0 = (bf16*)take((size_t)BB*K1*2);
  bf16* xcat1 = (bf16*)take((size_t)BB*K1*2);
  bf16* x2_0  = (bf16*)take((size_t)BB*K2*2);
  bf16* x2_1  = (bf16*)take((size_t)BB*K2*2);
  bf16* th    = (bf16*)take((size_t)BB*HH*2);
  float* c0   = (float*)take((size_t)BB*HH*4);
  float* c1   = (float*)take((size_t)BB*HH*4);
  float* prev = (float*)take((size_t)BB*X0*4);
  float* h1fa = (float*)take((size_t)BB*HH*4);
  float* h1fb = (float*)take((size_t)BB*HH*4);
  bf16* h1ba  = (bf16*)take((size_t)BB*HH*2);
  bf16* h1bb  = (bf16*)take((size_t)BB*HH*2);
  bf16* h2ba  = (bf16*)take((size_t)BB*HH*2);
  bf16* h2bb  = (bf16*)take((size_t)BB*HH*2);
  unsigned* bar = (unsigned*)take(2048);
  (void)ws_size; (void)in_sizes; (void)n_in; (void)out_size;

  prep_w0_kernel<<<(NG*K1+255)/256, 256, 0, stream>>>(Wih0, Whh0, W0cat);
  prep_w1_kernel<<<(NG*K2+255)/256, 256, 0, stream>>>(Wih1, Whh1, W1cat);
  cvt_kernel<<<(X0*HH+255)/256, 256, 0, stream>>>(Wlin, WlinB, X0*HH);
  cvt_kernel<<<(HH*HH+255)/256, 256, 0, stream>>>(A2a, A2aB, HH*HH);
  cvt_kernel<<<(HH*HH+255)/256, 256, 0, stream>>>(A2b, A2bB, HH*HH);
  cvt_kernel<<<(2*HH*HH+255)/256, 256, 0, stream>>>(A3a, A3aB, 2*HH*HH);
  cvt_kernel<<<(2*HH*HH+255)/256, 256, 0, stream>>>(A3b, A3bB, 2*HH*HH);
  prep_bias_kernel<<<(NG+255)/256, 256, 0, stream>>>(bih0, bhh0, bih1, bhh1, bias0, bias1, bar);
  init_x_kernel<<<(BB*X0+255)/256, 256, 0, stream>>>(z, prev, xcat1, out);
  r1_kernel<<<(BB*2*HH+255)/256, 256, 0, stream>>>(n0, A1a, b1a, A1b, b1b, h1fa, h1ba, h1fb, h1bb);
  rgemm_kernel<0><<<dim3(8,8), 256, 0, stream>>>(h1ba, A2aB, b2a, h1fa, h2ba, HH, nullptr, 0, nullptr, nullptr);
  rgemm_kernel<0><<<dim3(8,8), 256, 0, stream>>>(h1bb, A2bB, b2b, h1fb, h2bb, HH, nullptr, 0, nullptr, nullptr);
  rgemm_kernel<1><<<dim3(8,16), 256, 0, stream>>>(h2ba, A3aB, b3a, nullptr, xcat1 + X0, K1, x2_1 + HH, K2, nullptr, nullptr);
  rgemm_kernel<2><<<dim3(8,16), 256, 0, stream>>>(h2bb, A3bB, b3b, nullptr, nullptr, 0, nullptr, 0, c0, c1);

  PersistArgs pa;
  pa.W0r = W0cat; pa.W1r = W1cat; pa.Wl = WlinB;
  pa.bias0 = bias0; pa.bias1 = bias1;
  pa.c0 = c0; pa.c1 = c1;
  pa.xcat0 = xcat0; pa.xcat1 = xcat1; pa.x2_0 = x2_0; pa.x2_1 = x2_1; pa.th = th;
  pa.alphas = alphas; pa.betas = betas; pa.barals = barals; pa.snoise = snoise;
  pa.prev = prev; pa.out = out;
  pa.bar = bar;
  persist<<<256, 256, 0, stream>>>(pa);
}